// Round 13
// baseline (145.691 us; speedup 1.0000x reference)
//
#include <hip/hip_runtime.h>
#include <math.h>

typedef unsigned int uint32;

#define N_SURF 8192
#define M_QRY  32768
#define M_TOT  65536
#define HID    256

using f16x8  = __attribute__((ext_vector_type(8)))  _Float16;
using f32x16 = __attribute__((ext_vector_type(16))) float;

static __device__ __forceinline__ uint32 umin32(uint32 a, uint32 b) { return a < b ? a : b; }
static __device__ __forceinline__ uint32 umax32(uint32 a, uint32 b) { return a > b ? a : b; }

__device__ __forceinline__ void gload_lds16(const void* g, void* l) {
  __builtin_amdgcn_global_load_lds(
      (const __attribute__((address_space(1))) unsigned int*)g,
      (__attribute__((address_space(3))) unsigned int*)l, 16, 0, 0);
}

#define RMAP(r, half) (((r) & 3) + 8 * ((r) >> 2) + 4 * (half))

// ---- ws layout (float offsets) ----
// keys u32[524288] @0 ; AqG f16[1048576] @524288 ; BsG f16[131072] @1048576 ;
// c0G f32[65536] @1114112 ; h1f_hi @1179648 ; h1f_lo @2228224 ; h1C @3276800 ;
// w2f_hi @6422528 ; w2f_lo @6455296 ; w2tf_hi @6488064 ; w2tf_lo @6520832 ;
// sdf_part[256] @6553600 ; ori_part[256] @6553856 ; eg2[512] @6554112

// ---------------- K1: prep_all — queries, surface frags, W2 frags, layer-1 ----------------
__global__ __launch_bounds__(256) void prep_all(
    const float* __restrict__ sp,
    const float* __restrict__ offp, const float* __restrict__ nearp,
    const float* __restrict__ W1, const float* __restrict__ b1,
    const float* __restrict__ W2,
    _Float16* __restrict__ AqG, _Float16* __restrict__ BsG,
    float* __restrict__ c0G,
    _Float16* __restrict__ w2f_hi, _Float16* __restrict__ w2f_lo,
    _Float16* __restrict__ w2tf_hi, _Float16* __restrict__ w2tf_lo,
    _Float16* __restrict__ h1f_hi, _Float16* __restrict__ h1f_lo,
    _Float16* __restrict__ h1C) {
  int bid = blockIdx.x, tid = threadIdx.x;
  if (bid < 256) {                    // ---- query features ----
    int q = bid * 256 + tid;
    const float* p = (q < M_QRY) ? (offp + q * 3) : (nearp + (q - M_QRY) * 3);
    float x = p[0], y = p[1], z = p[2];
    _Float16 hx = (_Float16)x, hy = (_Float16)y, hz = (_Float16)z;
    _Float16 lx = (_Float16)(x - (float)hx);
    _Float16 ly = (_Float16)(y - (float)hy);
    _Float16 lz = (_Float16)(z - (float)hz);
    float tx = (float)hx + (float)lx, ty = (float)hy + (float)ly, tz = (float)hz + (float)lz;
    _Float16 av[16] = {hx, hy, hz, lx, ly, lz, hx, hy, hz, lx, ly, lz,
                       (_Float16)1.0f, (_Float16)1.0f, (_Float16)1.0f, (_Float16)0.0f};
    float4* dst = (float4*)&AqG[(size_t)q * 16];
    dst[0] = *(float4*)&av[0];
    dst[1] = *(float4*)&av[8];
    c0G[q] = 0.5f * (tx * tx + ty * ty + tz * tz);
  } else if (bid < 288) {             // ---- surface point features ----
    int i = (bid - 256) * 256 + tid;  // 0..8191
    float x = sp[i * 3 + 0], y = sp[i * 3 + 1], z = sp[i * 3 + 2];
    _Float16 hx = (_Float16)x, hy = (_Float16)y, hz = (_Float16)z;
    _Float16 lx = (_Float16)(x - (float)hx);
    _Float16 ly = (_Float16)(y - (float)hy);
    _Float16 lz = (_Float16)(z - (float)hz);
    float tx = (float)hx + (float)lx, ty = (float)hy + (float)ly, tz = (float)hz + (float)lz;
    float w = 0.5f * (tx * tx + ty * ty + tz * tz);
    _Float16 wh = (_Float16)w;
    float r1 = w - (float)wh;
    _Float16 wl = (_Float16)r1;
    _Float16 wll = (_Float16)(r1 - (float)wl);
    _Float16 nhx = -hx, nhy = -hy, nhz = -hz, nlx = -lx, nly = -ly, nlz = -lz;
    _Float16 b0[8] = {nhx, nhy, nhz, nhx, nhy, nhz, nlx, nly};            // k0..7
    _Float16 b1v[8] = {nlz, nlx, nly, nlz, wh, wl, wll, (_Float16)0.0f};  // k8..15
    int tile = i >> 5, pcol = i & 31;
    *(float4*)&BsG[(size_t)((tile * 2 + 0) * 32 + pcol) * 8] = *(float4*)&b0[0];
    *(float4*)&BsG[(size_t)((tile * 2 + 1) * 32 + pcol) * 8] = *(float4*)&b1v[0];
  } else if (bid < 352) {             // ---- W2 / W2^T fragment packs ----
    int u = (bid - 288) * 256 + tid;  // 0..16383
    int uu = u & 8191;
    int lane = uu & 63, su = uu >> 6;
    int cb = su >> 4, s = su & 15;
    int nl = lane & 31, hf = lane >> 5;
    float v[8];
    if (u < 8192) {
#pragma unroll
      for (int e = 0; e < 8; e++) v[e] = W2[(s * 16 + hf * 8 + e) * 256 + cb * 32 + nl];
    } else {
#pragma unroll
      for (int e = 0; e < 8; e++) v[e] = W2[(cb * 32 + nl) * 256 + s * 16 + hf * 8 + e];
    }
    _Float16 hi[8], lo[8];
#pragma unroll
    for (int e = 0; e < 8; e++) {
      _Float16 h = (_Float16)v[e];
      hi[e] = h; lo[e] = (_Float16)(v[e] - (float)h);
    }
    _Float16* dh = (u < 8192) ? w2f_hi : w2tf_hi;
    _Float16* dl = (u < 8192) ? w2f_lo : w2tf_lo;
    *(float4*)&dh[(size_t)uu * 8] = *(float4*)hi;
    *(float4*)&dl[(size_t)uu * 8] = *(float4*)lo;
  } else {                            // ---- layer-1 h1 frags + h1C ----
    int rb = bid - 352;               // 0..255
    int row = rb * 32 + (tid >> 3);
    int oct = tid & 7;
    float px = sp[row * 3 + 0], py = sp[row * 3 + 1], pz = sp[row * 3 + 2];
#pragma unroll
    for (int it = 0; it < 4; ++it) {
      int j0 = it * 64 + oct * 8;
      _Float16 hh[8], hl[8];
#pragma unroll
      for (int e = 0; e < 8; e++) {
        int j = j0 + e;
        float z = fmaf(px, W1[j], fmaf(py, W1[256 + j], fmaf(pz, W1[512 + j], b1[j])));
        float h = fmaxf(z, 0.f) + log1pf(expf(-fabsf(z)));
        _Float16 hi = (_Float16)h;
        hh[e] = hi; hl[e] = (_Float16)(h - (float)hi);
      }
      int s = it * 4 + (oct >> 1), hf = oct & 1;
      size_t uidx = ((size_t)(rb * 16 + s)) * 64 + (row & 31) + 32 * hf;
      *(float4*)&h1f_hi[uidx * 8] = *(float4*)hh;
      *(float4*)&h1f_lo[uidx * 8] = *(float4*)hl;
      *(float4*)&h1C[(size_t)row * 256 + j0] = *(float4*)hh;
    }
  }
}

// ---------------- K2: MFMA 2-NN scan — builtin MFMA + C++ tracker (AGPR-direct VALU) ----------------
#define TRACK2(d0v, d1v, s0v, s1v)                                        \
  _Pragma("unroll")                                                       \
  for (int r = 0; r < 16; r++) {                                          \
    uint32 kA = (__float_as_uint(d0v[r]) & vmask) | (uint32)(s0v);        \
    uint32 kB = (__float_as_uint(d1v[r]) & vmask) | (uint32)(s1v);        \
    b1[r] = umin32(b1[r], umin32(kA, kB));                                \
  }

__global__ __launch_bounds__(256) void scan_knn2(
    const float4* __restrict__ BsG,    // 8192*2 16B units, frag order
    const float4* __restrict__ AqG,
    const float* __restrict__ c0G,
    uint32* __restrict__ keys) {       // [4][65536][2]
  __shared__ __align__(16) float4 Bsh[2048];  // 32KB (2 x 1024 units)
  int tid = threadIdx.x;
  int lane = tid & 63, wid = tid >> 6;
  int col = lane & 31, half = lane >> 5;
  int seg = blockIdx.x >> 9;           // 0..3
  int qb  = blockIdx.x & 511;
  int qbase = qb * 128 + wid * 32;

  f16x8 afrag = ((const f16x8*)AqG)[(qbase + col) * 2 + half];
  f32x16 c0f;
#pragma unroll
  for (int r = 0; r < 16; r++) c0f[r] = c0G[qbase + RMAP(r, half)];
  uint32 b1[16];
#pragma unroll
  for (int r = 0; r < 16; r++) b1[r] = 0xFFFFFFFFu;

  const char* gseg = (const char*)(BsG + (size_t)seg * 4096);  // 2048 pts
  char* lbase = (char*)&Bsh[0];
#pragma unroll
  for (int i = 0; i < 4; i++)
    gload_lds16(gseg + (size_t)(0 * 1024 + i * 256 + tid) * 16,
                lbase + ((0 * 1024 + i * 256 + tid) * 16));
#pragma unroll
  for (int i = 0; i < 4; i++)
    gload_lds16(gseg + (size_t)(1 * 1024 + i * 256 + tid) * 16,
                lbase + ((1024 + i * 256 + tid) * 16));

  uint32 vmask;
  asm("v_mov_b32 %0, 0xFFFFE000" : "=v"(vmask));  // pin mask in a VGPR (opaque)
  int tseg = seg * 64;                 // global tile base (64 tiles / segment)
#pragma unroll 1
  for (int c = 0; c < 4; c++) {
    if (c < 3) asm volatile("s_waitcnt vmcnt(4)" ::: "memory");
    else       asm volatile("s_waitcnt vmcnt(0)" ::: "memory");
    __builtin_amdgcn_s_barrier();
    const f16x8* bbuf = (const f16x8*)&Bsh[(c & 1) * 1024];
    int tbase = tseg + c * 16;
    // A holds even pairs (tiles 4g+0,4g+1), B holds odd pairs (tiles 4g+2,4g+3).
    f16x8 fA0 = bbuf[0 * 64 + lane];
    f16x8 fA1 = bbuf[1 * 64 + lane];
    f32x16 dA0 = __builtin_amdgcn_mfma_f32_32x32x16_f16(afrag, fA0, c0f, 0, 0, 0);
    f32x16 dA1 = __builtin_amdgcn_mfma_f32_32x32x16_f16(afrag, fA1, c0f, 0, 0, 0);
    f16x8 fB0 = bbuf[2 * 64 + lane];
    f16x8 fB1 = bbuf[3 * 64 + lane];
    f32x16 dB0 = __builtin_amdgcn_mfma_f32_32x32x16_f16(afrag, fB0, c0f, 0, 0, 0);
    f32x16 dB1 = __builtin_amdgcn_mfma_f32_32x32x16_f16(afrag, fB1, c0f, 0, 0, 0);
#pragma unroll
    for (int g = 0; g < 3; g++) {
      TRACK2(dA0, dA1, tbase + 4 * g + 0, tbase + 4 * g + 1);
      fA0 = bbuf[(4 * g + 4) * 64 + lane];
      fA1 = bbuf[(4 * g + 5) * 64 + lane];
      dA0 = __builtin_amdgcn_mfma_f32_32x32x16_f16(afrag, fA0, c0f, 0, 0, 0);
      dA1 = __builtin_amdgcn_mfma_f32_32x32x16_f16(afrag, fA1, c0f, 0, 0, 0);
      TRACK2(dB0, dB1, tbase + 4 * g + 2, tbase + 4 * g + 3);
      fB0 = bbuf[(4 * g + 6) * 64 + lane];
      fB1 = bbuf[(4 * g + 7) * 64 + lane];
      dB0 = __builtin_amdgcn_mfma_f32_32x32x16_f16(afrag, fB0, c0f, 0, 0, 0);
      dB1 = __builtin_amdgcn_mfma_f32_32x32x16_f16(afrag, fB1, c0f, 0, 0, 0);
    }
    TRACK2(dA0, dA1, tbase + 12, tbase + 13);
    TRACK2(dB0, dB1, tbase + 14, tbase + 15);
    __builtin_amdgcn_s_barrier();
    if (c + 2 < 4) {
      int nc = c + 2;
#pragma unroll
      for (int i = 0; i < 4; i++)
        gload_lds16(gseg + (size_t)(nc * 1024 + i * 256 + tid) * 16,
                    lbase + (((nc & 1) * 1024 + i * 256 + tid) * 16));
    }
  }

  // tile-keys -> full-index keys: idx = tile*32 + col
#pragma unroll
  for (int r = 0; r < 16; r++) {
    uint32 t1 = b1[r];
    b1[r] = (t1 & 0xFFFFE000u) | (((t1 & 0xFFu) << 5) | (uint32)col);
  }
  uint32 b2[16];
#pragma unroll
  for (int r = 0; r < 16; r++) b2[r] = 0xFFFFFFFFu;
#pragma unroll
  for (int r = 0; r < 16; r++) {
#pragma unroll
    for (int m = 1; m <= 16; m <<= 1) {
      uint32 o1 = (uint32)__shfl_xor((int)b1[r], m, 64);
      uint32 o2 = (uint32)__shfl_xor((int)b2[r], m, 64);
      uint32 n1 = umin32(b1[r], o1);
      uint32 n2 = umin32(umax32(b1[r], o1), umin32(b2[r], o2));
      b1[r] = n1; b2[r] = n2;
    }
  }
  if (col == 0) {
#pragma unroll
    for (int r = 0; r < 16; r++) {
      int row = RMAP(r, half);
      keys[(size_t)seg * 131072 + (size_t)(qbase + row) * 2 + 0] = b1[r];
      keys[(size_t)seg * 131072 + (size_t)(qbase + row) * 2 + 1] = b2[r];
    }
  }
}

// ---------------- K3: merge 4 segs, signs, orientation partials ----------------
__global__ __launch_bounds__(256) void knn_finish(
    const uint32* __restrict__ keys,
    const float* __restrict__ sp, const float* __restrict__ sn,
    const float* __restrict__ offp, const float* __restrict__ nearp,
    const float* __restrict__ off_pred, const float* __restrict__ near_pred,
    float* __restrict__ part) {
  int q = blockIdx.x * 256 + threadIdx.x;
  bool isOff = q < M_QRY;
  const float* qp = isOff ? (offp + q * 3) : (nearp + (q - M_QRY) * 3);
  float qx = qp[0], qy = qp[1], qz = qp[2];
  uint32 m1 = 0xFFFFFFFFu, m2 = 0xFFFFFFFFu;
#pragma unroll
  for (int s = 0; s < 4; s++) {
    uint32 k1 = keys[(size_t)s * 131072 + (size_t)q * 2 + 0];
    uint32 k2 = keys[(size_t)s * 131072 + (size_t)q * 2 + 1];
    m2 = umin32(m2, umax32(m1, k1)); m1 = umin32(m1, k1);
    m2 = umin32(m2, umax32(m1, k2)); m1 = umin32(m1, k2);
  }
  int i1 = (int)(m1 & 8191u), i2 = (int)(m2 & 8191u);
  float d1 = (qx - sp[i1 * 3 + 0]) * sn[i1 * 3 + 0] +
             (qy - sp[i1 * 3 + 1]) * sn[i1 * 3 + 1] +
             (qz - sp[i1 * 3 + 2]) * sn[i1 * 3 + 2];
  float d2 = (qx - sp[i2 * 3 + 0]) * sn[i2 * 3 + 0] +
             (qy - sp[i2 * 3 + 1]) * sn[i2 * 3 + 1] +
             (qz - sp[i2 * 3 + 2]) * sn[i2 * 3 + 2];
  float m = d1 + d2;
  float sg = (m > 0.f) ? 1.f : ((m < 0.f) ? -1.f : 0.f);
  float pred = isOff ? off_pred[q] : near_pred[q - M_QRY];
  float contrib = fmaxf(0.f, -pred * sg);

  __shared__ float red[256];
  int t = threadIdx.x;
  red[t] = contrib;
  __syncthreads();
  for (int s = 128; s > 0; s >>= 1) {
    if (t < s) red[t] += red[t + s];
    __syncthreads();
  }
  if (t == 0) part[blockIdx.x] = red[0];
}

// ---------------- K4: fused GEMM1+GEMM2 — dz2 passes through LDS ----------------
__global__ __launch_bounds__(512) void gemm_fused(
    const _Float16* __restrict__ h1f_hi, const _Float16* __restrict__ h1f_lo,
    const _Float16* __restrict__ w2f_hi, const _Float16* __restrict__ w2f_lo,
    const _Float16* __restrict__ w2tf_hi, const _Float16* __restrict__ w2tf_lo,
    const _Float16* __restrict__ h1C, const float* __restrict__ W1,
    const float* __restrict__ b2, const float* __restrict__ W3,
    const float* __restrict__ b3, const float* __restrict__ sn,
    float* __restrict__ sdf_part,         // [256]
    float* __restrict__ eg2) {            // [256][2]
  __shared__ __align__(16) _Float16 tlds[8][2][32][40]; // 40KB
  __shared__ float predb[8][32];
  __shared__ float gb[8][32][3];
  int tid = threadIdx.x, lane = tid & 63, wid = tid >> 6;
  int rb = blockIdx.x;                    // 0..255
  int nl = lane & 31, half = lane >> 5;

  // ---------- phase 1: z2 = h1 @ W2 ----------
  {
    int cb = wid;
    f32x16 acc = {};
#pragma unroll
    for (int s = 0; s < 16; s++) {
      f16x8 ah = *(const f16x8*)&h1f_hi[(((size_t)rb * 16 + s) * 64 + lane) * 8];
      f16x8 al = *(const f16x8*)&h1f_lo[(((size_t)rb * 16 + s) * 64 + lane) * 8];
      f16x8 bh = *(const f16x8*)&w2f_hi[(((size_t)cb * 16 + s) * 64 + lane) * 8];
      f16x8 bl = *(const f16x8*)&w2f_lo[(((size_t)cb * 16 + s) * 64 + lane) * 8];
      acc = __builtin_amdgcn_mfma_f32_32x32x16_f16(ah, bh, acc, 0, 0, 0);
      acc = __builtin_amdgcn_mfma_f32_32x32x16_f16(al, bh, acc, 0, 0, 0);
      acc = __builtin_amdgcn_mfma_f32_32x32x16_f16(ah, bl, acc, 0, 0, 0);
    }
    int n = cb * 32 + nl;
    float b2n = b2[n], w3n = W3[n];
    float psum[16];
    _Float16 dh[16], dl[16];
#pragma unroll
    for (int r = 0; r < 16; r++) {
      float z = acc[r] + b2n;
      float h2 = fmaxf(z, 0.f) + log1pf(expf(-fabsf(z)));
      psum[r] = h2 * w3n;
      float dz2 = w3n * (1.f - expf(-h2));
      _Float16 hd = (_Float16)dz2;
      dh[r] = hd; dl[r] = (_Float16)(dz2 - (float)hd);
    }
#pragma unroll
    for (int r = 0; r < 16; r++) {
#pragma unroll
      for (int m = 1; m <= 16; m <<= 1) psum[r] += __shfl_xor(psum[r], m, 64);
    }
    if (nl == 0) {
#pragma unroll
      for (int r = 0; r < 16; r++) predb[cb][RMAP(r, half)] = psum[r];
    }
#pragma unroll
    for (int r = 0; r < 16; r++) {
      int rw = RMAP(r, half);
      tlds[wid][0][rw][nl] = dh[r];
      tlds[wid][1][rw][nl] = dl[r];
    }
  }
  __syncthreads();

  // ---------- phase 2: dh1 = dz2 @ W2^T ; grad ----------
  {
    int cb2 = wid;
    f32x16 acc = {};
#pragma unroll
    for (int s = 0; s < 16; s++) {
      f16x8 ah = *(const f16x8*)&tlds[s >> 1][0][nl][(s & 1) * 16 + half * 8];
      f16x8 al = *(const f16x8*)&tlds[s >> 1][1][nl][(s & 1) * 16 + half * 8];
      f16x8 bh = *(const f16x8*)&w2tf_hi[(((size_t)cb2 * 16 + s) * 64 + lane) * 8];
      f16x8 bl = *(const f16x8*)&w2tf_lo[(((size_t)cb2 * 16 + s) * 64 + lane) * 8];
      acc = __builtin_amdgcn_mfma_f32_32x32x16_f16(ah, bh, acc, 0, 0, 0);
      acc = __builtin_amdgcn_mfma_f32_32x32x16_f16(al, bh, acc, 0, 0, 0);
      acc = __builtin_amdgcn_mfma_f32_32x32x16_f16(ah, bl, acc, 0, 0, 0);
    }
    int j = cb2 * 32 + nl;
    float w10 = W1[j], w11 = W1[256 + j], w12 = W1[512 + j];
    float gx[16], gy[16], gz[16];
#pragma unroll
    for (int r = 0; r < 16; r++) {
      int row = rb * 32 + RMAP(r, half);
      float h1 = (float)h1C[(size_t)row * 256 + j];
      float s1 = 1.f - expf(-h1);
      float dz1 = acc[r] * s1;
      gx[r] = dz1 * w10; gy[r] = dz1 * w11; gz[r] = dz1 * w12;
    }
#pragma unroll
    for (int r = 0; r < 16; r++) {
#pragma unroll
      for (int m = 1; m <= 16; m <<= 1) {
        gx[r] += __shfl_xor(gx[r], m, 64);
        gy[r] += __shfl_xor(gy[r], m, 64);
        gz[r] += __shfl_xor(gz[r], m, 64);
      }
    }
    if (nl == 0) {
#pragma unroll
      for (int r = 0; r < 16; r++) {
        int row32 = RMAP(r, half);
        gb[cb2][row32][0] = gx[r];
        gb[cb2][row32][1] = gy[r];
        gb[cb2][row32][2] = gz[r];
      }
    }
  }
  __syncthreads();

  if (tid < 64) {
    int row32 = tid & 31;
    float p = b3[0];
    float sgx = 0.f, sgy = 0.f, sgz = 0.f;
#pragma unroll
    for (int c8 = 0; c8 < 8; c8++) {
      p += predb[c8][row32];
      sgx += gb[c8][row32][0];
      sgy += gb[c8][row32][1];
      sgz += gb[c8][row32][2];
    }
    int row = rb * 32 + row32;
    float n0 = sn[row * 3 + 0], n1 = sn[row * 3 + 1], n2 = sn[row * 3 + 2];
    float nrm = sqrtf(sgx * sgx + sgy * sgy + sgz * sgz);
    float ee = (nrm - 1.f) * (nrm - 1.f);
    float gg = (sgx - n0) * (sgx - n0) + (sgy - n1) * (sgy - n1) + (sgz - n2) * (sgz - n2);
    float vee = (tid < 32) ? ee : 0.f;
    float vgg = (tid < 32) ? gg : 0.f;
    float vsq = (tid < 32) ? p * p : 0.f;
    for (int off = 32; off > 0; off >>= 1) {
      vee += __shfl_down(vee, off);
      vgg += __shfl_down(vgg, off);
      vsq += __shfl_down(vsq, off);
    }
    if (tid == 0) {
      sdf_part[rb] = vsq;
      eg2[rb * 2 + 0] = vee;
      eg2[rb * 2 + 1] = vgg;
    }
  }
}

// ---------------- K5: final reduce (tiny) ----------------
__global__ __launch_bounds__(256) void finalize(
    const float* __restrict__ sdf_part,   // 256
    const float* __restrict__ ori_part,   // 256
    const float* __restrict__ eg2,        // 512
    float* __restrict__ out) {
  __shared__ float red[256];
  int t = threadIdx.x;
  float s_sdf = sdf_part[t];
  float s_ori = (t < 128) ? ori_part[t] : 0.f;
  float s_near = (t < 128) ? ori_part[128 + t] : 0.f;
  float s_eik = eg2[t * 2 + 0];
  float s_gn = eg2[t * 2 + 1];

  float S[5];
  float vals[5] = {s_sdf, s_ori, s_near, s_eik, s_gn};
  for (int v = 0; v < 5; v++) {
    red[t] = vals[v];
    __syncthreads();
    for (int s = 128; s > 0; s >>= 1) {
      if (t < s) red[t] += red[t + s];
      __syncthreads();
    }
    S[v] = red[0];
    __syncthreads();
  }
  if (t == 0) {
    float sdf = S[0] / 8192.f;
    float ori = S[1] / 32768.f;
    float nearo = S[2] / 32768.f;
    float eik = S[3] / 8192.f;
    float gn = S[4] / 24576.f;
    out[0] = 7000.f * sdf + 600.f * eik + 500.f * ori + 10.f * nearo + 200.f * gn;
    out[1] = sdf;
    out[2] = eik;
    out[3] = ori;
    out[4] = nearo;
    out[5] = gn;
  }
}

extern "C" void kernel_launch(void* const* d_in, const int* in_sizes, int n_in,
                              void* d_out, int out_size, void* d_ws, size_t ws_size,
                              hipStream_t stream) {
  const float* sp       = (const float*)d_in[0];
  const float* sn       = (const float*)d_in[1];
  const float* offp     = (const float*)d_in[2];
  const float* nearp    = (const float*)d_in[3];
  const float* off_pred = (const float*)d_in[4];
  const float* near_pred= (const float*)d_in[5];
  const float* W1 = (const float*)d_in[6];
  const float* b1 = (const float*)d_in[7];
  const float* W2 = (const float*)d_in[8];
  const float* b2 = (const float*)d_in[9];
  const float* W3 = (const float*)d_in[10];
  const float* b3 = (const float*)d_in[11];

  float* ws = (float*)d_ws;
  uint32* keys     = (uint32*)ws;                 // 524288 u32 @0
  _Float16* AqG    = (_Float16*)(ws + 524288);    // 1048576 f16
  _Float16* BsG    = (_Float16*)(ws + 1048576);   // 131072 f16
  float* c0G       = ws + 1114112;                // 65536 fl
  _Float16* h1f_hi = (_Float16*)(ws + 1179648);   // 2097152 f16 each
  _Float16* h1f_lo = (_Float16*)(ws + 2228224);
  _Float16* h1C    = (_Float16*)(ws + 3276800);
  _Float16* w2f_hi = (_Float16*)(ws + 6422528);   // 65536 f16 each
  _Float16* w2f_lo = (_Float16*)(ws + 6455296);
  _Float16* w2tf_hi= (_Float16*)(ws + 6488064);
  _Float16* w2tf_lo= (_Float16*)(ws + 6520832);
  float* sdf_part  = ws + 6553600;                // 256
  float* ori_part  = ws + 6553856;                // 256
  float* eg2       = ws + 6554112;                // 512
  float* out = (float*)d_out;

  prep_all<<<608, 256, 0, stream>>>(sp, offp, nearp, W1, b1, W2,
                                    AqG, BsG, c0G,
                                    w2f_hi, w2f_lo, w2tf_hi, w2tf_lo,
                                    h1f_hi, h1f_lo, h1C);
  scan_knn2<<<2048, 256, 0, stream>>>((const float4*)BsG, (const float4*)AqG, c0G, keys);
  knn_finish<<<256, 256, 0, stream>>>(keys, sp, sn, offp, nearp, off_pred, near_pred, ori_part);
  gemm_fused<<<256, 512, 0, stream>>>(h1f_hi, h1f_lo, w2f_hi, w2f_lo,
                                      w2tf_hi, w2tf_lo, h1C, W1,
                                      b2, W3, b3, sn, sdf_part, eg2);
  finalize<<<1, 256, 0, stream>>>(sdf_part, ori_part, eg2, out);
}

// Round 14
// 83.131 us; speedup vs baseline: 1.7525x; 1.7525x over previous
//
#include <hip/hip_runtime.h>
#include <math.h>

typedef unsigned int uint32;

#define N_SURF 8192
#define M_QRY  32768
#define M_TOT  65536
#define HID    256

using f16x8  = __attribute__((ext_vector_type(8)))  _Float16;
using f32x16 = __attribute__((ext_vector_type(16))) float;

static __device__ __forceinline__ uint32 umin32(uint32 a, uint32 b) { return a < b ? a : b; }
static __device__ __forceinline__ uint32 umax32(uint32 a, uint32 b) { return a > b ? a : b; }

__device__ __forceinline__ void gload_lds16(const void* g, void* l) {
  __builtin_amdgcn_global_load_lds(
      (const __attribute__((address_space(1))) unsigned int*)g,
      (__attribute__((address_space(3))) unsigned int*)l, 16, 0, 0);
}

// MFMA with destination in plain "v"-class regs (gfx950 unified file).
static __device__ __forceinline__ f32x16 mfma_v(f16x8 a, f16x8 b, f32x16 c) {
  f32x16 d;
  asm("v_mfma_f32_32x32x16_f16 %0, %1, %2, %3"
      : "=&v"(d) : "v"(a), "v"(b), "v"(c));
  return d;
}

#define RMAP(r, half) (((r) & 3) + 8 * ((r) >> 2) + 4 * (half))

// ---- ws layout (float offsets) ----
// keys u32[524288] @0 ; AqG f16[1048576] @524288 ; BsG f16[131072] @1048576 ;
// c0G f32[65536] @1114112 ; h1f_hi @1179648 ; h1f_lo @2228224 ; h1C @3276800 ;
// w2f_hi @6422528 ; w2f_lo @6455296 ; w2tf_hi @6488064 ; w2tf_lo @6520832 ;
// sdf_part[256] @6553600 ; ori_part[256] @6553856 ; eg2[512] @6554112

// ---------------- K1: prep_all — queries, surface frags, W2 frags, layer-1 ----------------
__global__ __launch_bounds__(256) void prep_all(
    const float* __restrict__ sp,
    const float* __restrict__ offp, const float* __restrict__ nearp,
    const float* __restrict__ W1, const float* __restrict__ b1,
    const float* __restrict__ W2,
    _Float16* __restrict__ AqG, _Float16* __restrict__ BsG,
    float* __restrict__ c0G,
    _Float16* __restrict__ w2f_hi, _Float16* __restrict__ w2f_lo,
    _Float16* __restrict__ w2tf_hi, _Float16* __restrict__ w2tf_lo,
    _Float16* __restrict__ h1f_hi, _Float16* __restrict__ h1f_lo,
    _Float16* __restrict__ h1C) {
  int bid = blockIdx.x, tid = threadIdx.x;
  if (bid < 256) {                    // ---- query features ----
    int q = bid * 256 + tid;
    const float* p = (q < M_QRY) ? (offp + q * 3) : (nearp + (q - M_QRY) * 3);
    float x = p[0], y = p[1], z = p[2];
    _Float16 hx = (_Float16)x, hy = (_Float16)y, hz = (_Float16)z;
    _Float16 lx = (_Float16)(x - (float)hx);
    _Float16 ly = (_Float16)(y - (float)hy);
    _Float16 lz = (_Float16)(z - (float)hz);
    float tx = (float)hx + (float)lx, ty = (float)hy + (float)ly, tz = (float)hz + (float)lz;
    _Float16 av[16] = {hx, hy, hz, lx, ly, lz, hx, hy, hz, lx, ly, lz,
                       (_Float16)1.0f, (_Float16)1.0f, (_Float16)1.0f, (_Float16)0.0f};
    float4* dst = (float4*)&AqG[(size_t)q * 16];
    dst[0] = *(float4*)&av[0];
    dst[1] = *(float4*)&av[8];
    c0G[q] = 0.5f * (tx * tx + ty * ty + tz * tz);
  } else if (bid < 288) {             // ---- surface point features ----
    int i = (bid - 256) * 256 + tid;  // 0..8191
    float x = sp[i * 3 + 0], y = sp[i * 3 + 1], z = sp[i * 3 + 2];
    _Float16 hx = (_Float16)x, hy = (_Float16)y, hz = (_Float16)z;
    _Float16 lx = (_Float16)(x - (float)hx);
    _Float16 ly = (_Float16)(y - (float)hy);
    _Float16 lz = (_Float16)(z - (float)hz);
    float tx = (float)hx + (float)lx, ty = (float)hy + (float)ly, tz = (float)hz + (float)lz;
    float w = 0.5f * (tx * tx + ty * ty + tz * tz);
    _Float16 wh = (_Float16)w;
    float r1 = w - (float)wh;
    _Float16 wl = (_Float16)r1;
    _Float16 wll = (_Float16)(r1 - (float)wl);
    _Float16 nhx = -hx, nhy = -hy, nhz = -hz, nlx = -lx, nly = -ly, nlz = -lz;
    _Float16 b0[8] = {nhx, nhy, nhz, nhx, nhy, nhz, nlx, nly};            // k0..7
    _Float16 b1v[8] = {nlz, nlx, nly, nlz, wh, wl, wll, (_Float16)0.0f};  // k8..15
    int tile = i >> 5, pcol = i & 31;
    *(float4*)&BsG[(size_t)((tile * 2 + 0) * 32 + pcol) * 8] = *(float4*)&b0[0];
    *(float4*)&BsG[(size_t)((tile * 2 + 1) * 32 + pcol) * 8] = *(float4*)&b1v[0];
  } else if (bid < 352) {             // ---- W2 / W2^T fragment packs ----
    int u = (bid - 288) * 256 + tid;  // 0..16383
    int uu = u & 8191;
    int lane = uu & 63, su = uu >> 6;
    int cb = su >> 4, s = su & 15;
    int nl = lane & 31, hf = lane >> 5;
    float v[8];
    if (u < 8192) {
#pragma unroll
      for (int e = 0; e < 8; e++) v[e] = W2[(s * 16 + hf * 8 + e) * 256 + cb * 32 + nl];
    } else {
#pragma unroll
      for (int e = 0; e < 8; e++) v[e] = W2[(cb * 32 + nl) * 256 + s * 16 + hf * 8 + e];
    }
    _Float16 hi[8], lo[8];
#pragma unroll
    for (int e = 0; e < 8; e++) {
      _Float16 h = (_Float16)v[e];
      hi[e] = h; lo[e] = (_Float16)(v[e] - (float)h);
    }
    _Float16* dh = (u < 8192) ? w2f_hi : w2tf_hi;
    _Float16* dl = (u < 8192) ? w2f_lo : w2tf_lo;
    *(float4*)&dh[(size_t)uu * 8] = *(float4*)hi;
    *(float4*)&dl[(size_t)uu * 8] = *(float4*)lo;
  } else {                            // ---- layer-1 h1 frags + h1C ----
    int rb = bid - 352;               // 0..255
    int row = rb * 32 + (tid >> 3);
    int oct = tid & 7;
    float px = sp[row * 3 + 0], py = sp[row * 3 + 1], pz = sp[row * 3 + 2];
#pragma unroll
    for (int it = 0; it < 4; ++it) {
      int j0 = it * 64 + oct * 8;
      _Float16 hh[8], hl[8];
#pragma unroll
      for (int e = 0; e < 8; e++) {
        int j = j0 + e;
        float z = fmaf(px, W1[j], fmaf(py, W1[256 + j], fmaf(pz, W1[512 + j], b1[j])));
        float h = fmaxf(z, 0.f) + log1pf(expf(-fabsf(z)));
        _Float16 hi = (_Float16)h;
        hh[e] = hi; hl[e] = (_Float16)(h - (float)hi);
      }
      int s = it * 4 + (oct >> 1), hf = oct & 1;
      size_t uidx = ((size_t)(rb * 16 + s)) * 64 + (row & 31) + 32 * hf;
      *(float4*)&h1f_hi[uidx * 8] = *(float4*)hh;
      *(float4*)&h1f_lo[uidx * 8] = *(float4*)hl;
      *(float4*)&h1C[(size_t)row * 256 + j0] = *(float4*)hh;
    }
  }
}

// ---------------- K2: MFMA 2-NN scan — A/B alternating pairs (r10 best) ----------------
#define TRACK2(d0v, d1v, s0v, s1v)                                        \
  _Pragma("unroll")                                                       \
  for (int r = 0; r < 16; r++) {                                          \
    uint32 kA, kB;                                                        \
    asm("v_and_or_b32 %0, %3, %5, %6\n\t"                                 \
        "v_and_or_b32 %1, %4, %5, %7\n\t"                                 \
        "v_min3_u32 %2, %2, %0, %1"                                       \
        : "=&v"(kA), "=&v"(kB), "+v"(b1[r])                               \
        : "v"(d0v[r]), "v"(d1v[r]), "v"(vmask), "s"(s0v), "s"(s1v));      \
  }

__global__ __launch_bounds__(256) void scan_knn2(
    const float4* __restrict__ BsG,    // 8192*2 16B units, frag order
    const float4* __restrict__ AqG,
    const float* __restrict__ c0G,
    uint32* __restrict__ keys) {       // [4][65536][2]
  __shared__ __align__(16) float4 Bsh[2048];  // 32KB (2 x 1024 units)
  int tid = threadIdx.x;
  int lane = tid & 63, wid = tid >> 6;
  int col = lane & 31, half = lane >> 5;
  int seg = blockIdx.x >> 9;           // 0..3
  int qb  = blockIdx.x & 511;
  int qbase = qb * 128 + wid * 32;

  f16x8 afrag = ((const f16x8*)AqG)[(qbase + col) * 2 + half];
  f32x16 c0f;
#pragma unroll
  for (int r = 0; r < 16; r++) c0f[r] = c0G[qbase + RMAP(r, half)];
  uint32 b1[16];
#pragma unroll
  for (int r = 0; r < 16; r++) b1[r] = 0xFFFFFFFFu;

  const char* gseg = (const char*)(BsG + (size_t)seg * 4096);  // 2048 pts
  char* lbase = (char*)&Bsh[0];
#pragma unroll
  for (int i = 0; i < 4; i++)
    gload_lds16(gseg + (size_t)(0 * 1024 + i * 256 + tid) * 16,
                lbase + ((0 * 1024 + i * 256 + tid) * 16));
#pragma unroll
  for (int i = 0; i < 4; i++)
    gload_lds16(gseg + (size_t)(1 * 1024 + i * 256 + tid) * 16,
                lbase + ((1024 + i * 256 + tid) * 16));

  uint32 vmask = 0xFFFFE000u;
  int tseg = seg * 64;                 // global tile base (64 tiles / segment)
#pragma unroll 1
  for (int c = 0; c < 4; c++) {
    if (c < 3) asm volatile("s_waitcnt vmcnt(4)" ::: "memory");
    else       asm volatile("s_waitcnt vmcnt(0)" ::: "memory");
    __builtin_amdgcn_s_barrier();
    const f16x8* bbuf = (const f16x8*)&Bsh[(c & 1) * 1024];
    int tbase = tseg + c * 16;
    // A holds even pairs (tiles 4g+0,4g+1), B holds odd pairs (tiles 4g+2,4g+3).
    f16x8 fA0 = bbuf[0 * 64 + lane];
    f16x8 fA1 = bbuf[1 * 64 + lane];
    f32x16 dA0 = mfma_v(afrag, fA0, c0f);
    f32x16 dA1 = mfma_v(afrag, fA1, c0f);
    f16x8 fB0 = bbuf[2 * 64 + lane];
    f16x8 fB1 = bbuf[3 * 64 + lane];
    f32x16 dB0 = mfma_v(afrag, fB0, c0f);
    f32x16 dB1 = mfma_v(afrag, fB1, c0f);
#pragma unroll
    for (int g = 0; g < 3; g++) {
      TRACK2(dA0, dA1, tbase + 4 * g + 0, tbase + 4 * g + 1);
      fA0 = bbuf[(4 * g + 4) * 64 + lane];
      fA1 = bbuf[(4 * g + 5) * 64 + lane];
      dA0 = mfma_v(afrag, fA0, c0f);
      dA1 = mfma_v(afrag, fA1, c0f);
      TRACK2(dB0, dB1, tbase + 4 * g + 2, tbase + 4 * g + 3);
      fB0 = bbuf[(4 * g + 6) * 64 + lane];
      fB1 = bbuf[(4 * g + 7) * 64 + lane];
      dB0 = mfma_v(afrag, fB0, c0f);
      dB1 = mfma_v(afrag, fB1, c0f);
    }
    TRACK2(dA0, dA1, tbase + 12, tbase + 13);
    TRACK2(dB0, dB1, tbase + 14, tbase + 15);
    __builtin_amdgcn_s_barrier();
    if (c + 2 < 4) {
      int nc = c + 2;
#pragma unroll
      for (int i = 0; i < 4; i++)
        gload_lds16(gseg + (size_t)(nc * 1024 + i * 256 + tid) * 16,
                    lbase + (((nc & 1) * 1024 + i * 256 + tid) * 16));
    }
  }

  // tile-keys -> full-index keys: idx = tile*32 + col
#pragma unroll
  for (int r = 0; r < 16; r++) {
    uint32 t1 = b1[r];
    b1[r] = (t1 & 0xFFFFE000u) | (((t1 & 0xFFu) << 5) | (uint32)col);
  }
  uint32 b2[16];
#pragma unroll
  for (int r = 0; r < 16; r++) b2[r] = 0xFFFFFFFFu;
#pragma unroll
  for (int r = 0; r < 16; r++) {
#pragma unroll
    for (int m = 1; m <= 16; m <<= 1) {
      uint32 o1 = (uint32)__shfl_xor((int)b1[r], m, 64);
      uint32 o2 = (uint32)__shfl_xor((int)b2[r], m, 64);
      uint32 n1 = umin32(b1[r], o1);
      uint32 n2 = umin32(umax32(b1[r], o1), umin32(b2[r], o2));
      b1[r] = n1; b2[r] = n2;
    }
  }
  if (col == 0) {
#pragma unroll
    for (int r = 0; r < 16; r++) {
      int row = RMAP(r, half);
      keys[(size_t)seg * 131072 + (size_t)(qbase + row) * 2 + 0] = b1[r];
      keys[(size_t)seg * 131072 + (size_t)(qbase + row) * 2 + 1] = b2[r];
    }
  }
}

// ---------------- K3: merge 4 segs, signs, orientation partials ----------------
__global__ __launch_bounds__(256) void knn_finish(
    const uint32* __restrict__ keys,
    const float* __restrict__ sp, const float* __restrict__ sn,
    const float* __restrict__ offp, const float* __restrict__ nearp,
    const float* __restrict__ off_pred, const float* __restrict__ near_pred,
    float* __restrict__ part) {
  int q = blockIdx.x * 256 + threadIdx.x;
  bool isOff = q < M_QRY;
  const float* qp = isOff ? (offp + q * 3) : (nearp + (q - M_QRY) * 3);
  float qx = qp[0], qy = qp[1], qz = qp[2];
  uint32 m1 = 0xFFFFFFFFu, m2 = 0xFFFFFFFFu;
#pragma unroll
  for (int s = 0; s < 4; s++) {
    uint32 k1 = keys[(size_t)s * 131072 + (size_t)q * 2 + 0];
    uint32 k2 = keys[(size_t)s * 131072 + (size_t)q * 2 + 1];
    m2 = umin32(m2, umax32(m1, k1)); m1 = umin32(m1, k1);
    m2 = umin32(m2, umax32(m1, k2)); m1 = umin32(m1, k2);
  }
  int i1 = (int)(m1 & 8191u), i2 = (int)(m2 & 8191u);
  float d1 = (qx - sp[i1 * 3 + 0]) * sn[i1 * 3 + 0] +
             (qy - sp[i1 * 3 + 1]) * sn[i1 * 3 + 1] +
             (qz - sp[i1 * 3 + 2]) * sn[i1 * 3 + 2];
  float d2 = (qx - sp[i2 * 3 + 0]) * sn[i2 * 3 + 0] +
             (qy - sp[i2 * 3 + 1]) * sn[i2 * 3 + 1] +
             (qz - sp[i2 * 3 + 2]) * sn[i2 * 3 + 2];
  float m = d1 + d2;
  float sg = (m > 0.f) ? 1.f : ((m < 0.f) ? -1.f : 0.f);
  float pred = isOff ? off_pred[q] : near_pred[q - M_QRY];
  float contrib = fmaxf(0.f, -pred * sg);

  __shared__ float red[256];
  int t = threadIdx.x;
  red[t] = contrib;
  __syncthreads();
  for (int s = 128; s > 0; s >>= 1) {
    if (t < s) red[t] += red[t + s];
    __syncthreads();
  }
  if (t == 0) part[blockIdx.x] = red[0];
}

// ---------------- K4: fused GEMM1+GEMM2 — dz2 passes through LDS ----------------
__global__ __launch_bounds__(512) void gemm_fused(
    const _Float16* __restrict__ h1f_hi, const _Float16* __restrict__ h1f_lo,
    const _Float16* __restrict__ w2f_hi, const _Float16* __restrict__ w2f_lo,
    const _Float16* __restrict__ w2tf_hi, const _Float16* __restrict__ w2tf_lo,
    const _Float16* __restrict__ h1C, const float* __restrict__ W1,
    const float* __restrict__ b2, const float* __restrict__ W3,
    const float* __restrict__ b3, const float* __restrict__ sn,
    float* __restrict__ sdf_part,         // [256]
    float* __restrict__ eg2) {            // [256][2]
  __shared__ __align__(16) _Float16 tlds[8][2][32][40]; // 40KB
  __shared__ float predb[8][32];
  __shared__ float gb[8][32][3];
  int tid = threadIdx.x, lane = tid & 63, wid = tid >> 6;
  int rb = blockIdx.x;                    // 0..255
  int nl = lane & 31, half = lane >> 5;

  // ---------- phase 1: z2 = h1 @ W2 ----------
  {
    int cb = wid;
    f32x16 acc = {};
#pragma unroll
    for (int s = 0; s < 16; s++) {
      f16x8 ah = *(const f16x8*)&h1f_hi[(((size_t)rb * 16 + s) * 64 + lane) * 8];
      f16x8 al = *(const f16x8*)&h1f_lo[(((size_t)rb * 16 + s) * 64 + lane) * 8];
      f16x8 bh = *(const f16x8*)&w2f_hi[(((size_t)cb * 16 + s) * 64 + lane) * 8];
      f16x8 bl = *(const f16x8*)&w2f_lo[(((size_t)cb * 16 + s) * 64 + lane) * 8];
      acc = __builtin_amdgcn_mfma_f32_32x32x16_f16(ah, bh, acc, 0, 0, 0);
      acc = __builtin_amdgcn_mfma_f32_32x32x16_f16(al, bh, acc, 0, 0, 0);
      acc = __builtin_amdgcn_mfma_f32_32x32x16_f16(ah, bl, acc, 0, 0, 0);
    }
    int n = cb * 32 + nl;
    float b2n = b2[n], w3n = W3[n];
    float psum[16];
    _Float16 dh[16], dl[16];
#pragma unroll
    for (int r = 0; r < 16; r++) {
      float z = acc[r] + b2n;
      float h2 = fmaxf(z, 0.f) + log1pf(expf(-fabsf(z)));
      psum[r] = h2 * w3n;
      float dz2 = w3n * (1.f - expf(-h2));
      _Float16 hd = (_Float16)dz2;
      dh[r] = hd; dl[r] = (_Float16)(dz2 - (float)hd);
    }
#pragma unroll
    for (int r = 0; r < 16; r++) {
#pragma unroll
      for (int m = 1; m <= 16; m <<= 1) psum[r] += __shfl_xor(psum[r], m, 64);
    }
    if (nl == 0) {
#pragma unroll
      for (int r = 0; r < 16; r++) predb[cb][RMAP(r, half)] = psum[r];
    }
#pragma unroll
    for (int r = 0; r < 16; r++) {
      int rw = RMAP(r, half);
      tlds[wid][0][rw][nl] = dh[r];
      tlds[wid][1][rw][nl] = dl[r];
    }
  }
  __syncthreads();

  // ---------- phase 2: dh1 = dz2 @ W2^T ; grad ----------
  {
    int cb2 = wid;
    f32x16 acc = {};
#pragma unroll
    for (int s = 0; s < 16; s++) {
      f16x8 ah = *(const f16x8*)&tlds[s >> 1][0][nl][(s & 1) * 16 + half * 8];
      f16x8 al = *(const f16x8*)&tlds[s >> 1][1][nl][(s & 1) * 16 + half * 8];
      f16x8 bh = *(const f16x8*)&w2tf_hi[(((size_t)cb2 * 16 + s) * 64 + lane) * 8];
      f16x8 bl = *(const f16x8*)&w2tf_lo[(((size_t)cb2 * 16 + s) * 64 + lane) * 8];
      acc = __builtin_amdgcn_mfma_f32_32x32x16_f16(ah, bh, acc, 0, 0, 0);
      acc = __builtin_amdgcn_mfma_f32_32x32x16_f16(al, bh, acc, 0, 0, 0);
      acc = __builtin_amdgcn_mfma_f32_32x32x16_f16(ah, bl, acc, 0, 0, 0);
    }
    int j = cb2 * 32 + nl;
    float w10 = W1[j], w11 = W1[256 + j], w12 = W1[512 + j];
    float gx[16], gy[16], gz[16];
#pragma unroll
    for (int r = 0; r < 16; r++) {
      int row = rb * 32 + RMAP(r, half);
      float h1 = (float)h1C[(size_t)row * 256 + j];
      float s1 = 1.f - expf(-h1);
      float dz1 = acc[r] * s1;
      gx[r] = dz1 * w10; gy[r] = dz1 * w11; gz[r] = dz1 * w12;
    }
#pragma unroll
    for (int r = 0; r < 16; r++) {
#pragma unroll
      for (int m = 1; m <= 16; m <<= 1) {
        gx[r] += __shfl_xor(gx[r], m, 64);
        gy[r] += __shfl_xor(gy[r], m, 64);
        gz[r] += __shfl_xor(gz[r], m, 64);
      }
    }
    if (nl == 0) {
#pragma unroll
      for (int r = 0; r < 16; r++) {
        int row32 = RMAP(r, half);
        gb[cb2][row32][0] = gx[r];
        gb[cb2][row32][1] = gy[r];
        gb[cb2][row32][2] = gz[r];
      }
    }
  }
  __syncthreads();

  if (tid < 64) {
    int row32 = tid & 31;
    float p = b3[0];
    float sgx = 0.f, sgy = 0.f, sgz = 0.f;
#pragma unroll
    for (int c8 = 0; c8 < 8; c8++) {
      p += predb[c8][row32];
      sgx += gb[c8][row32][0];
      sgy += gb[c8][row32][1];
      sgz += gb[c8][row32][2];
    }
    int row = rb * 32 + row32;
    float n0 = sn[row * 3 + 0], n1 = sn[row * 3 + 1], n2 = sn[row * 3 + 2];
    float nrm = sqrtf(sgx * sgx + sgy * sgy + sgz * sgz);
    float ee = (nrm - 1.f) * (nrm - 1.f);
    float gg = (sgx - n0) * (sgx - n0) + (sgy - n1) * (sgy - n1) + (sgz - n2) * (sgz - n2);
    float vee = (tid < 32) ? ee : 0.f;
    float vgg = (tid < 32) ? gg : 0.f;
    float vsq = (tid < 32) ? p * p : 0.f;
    for (int off = 32; off > 0; off >>= 1) {
      vee += __shfl_down(vee, off);
      vgg += __shfl_down(vgg, off);
      vsq += __shfl_down(vsq, off);
    }
    if (tid == 0) {
      sdf_part[rb] = vsq;
      eg2[rb * 2 + 0] = vee;
      eg2[rb * 2 + 1] = vgg;
    }
  }
}

// ---------------- K5: final reduce (tiny) ----------------
__global__ __launch_bounds__(256) void finalize(
    const float* __restrict__ sdf_part,   // 256
    const float* __restrict__ ori_part,   // 256
    const float* __restrict__ eg2,        // 512
    float* __restrict__ out) {
  __shared__ float red[256];
  int t = threadIdx.x;
  float s_sdf = sdf_part[t];
  float s_ori = (t < 128) ? ori_part[t] : 0.f;
  float s_near = (t < 128) ? ori_part[128 + t] : 0.f;
  float s_eik = eg2[t * 2 + 0];
  float s_gn = eg2[t * 2 + 1];

  float S[5];
  float vals[5] = {s_sdf, s_ori, s_near, s_eik, s_gn};
  for (int v = 0; v < 5; v++) {
    red[t] = vals[v];
    __syncthreads();
    for (int s = 128; s > 0; s >>= 1) {
      if (t < s) red[t] += red[t + s];
      __syncthreads();
    }
    S[v] = red[0];
    __syncthreads();
  }
  if (t == 0) {
    float sdf = S[0] / 8192.f;
    float ori = S[1] / 32768.f;
    float nearo = S[2] / 32768.f;
    float eik = S[3] / 8192.f;
    float gn = S[4] / 24576.f;
    out[0] = 7000.f * sdf + 600.f * eik + 500.f * ori + 10.f * nearo + 200.f * gn;
    out[1] = sdf;
    out[2] = eik;
    out[3] = ori;
    out[4] = nearo;
    out[5] = gn;
  }
}

extern "C" void kernel_launch(void* const* d_in, const int* in_sizes, int n_in,
                              void* d_out, int out_size, void* d_ws, size_t ws_size,
                              hipStream_t stream) {
  const float* sp       = (const float*)d_in[0];
  const float* sn       = (const float*)d_in[1];
  const float* offp     = (const float*)d_in[2];
  const float* nearp    = (const float*)d_in[3];
  const float* off_pred = (const float*)d_in[4];
  const float* near_pred= (const float*)d_in[5];
  const float* W1 = (const float*)d_in[6];
  const float* b1 = (const float*)d_in[7];
  const float* W2 = (const float*)d_in[8];
  const float* b2 = (const float*)d_in[9];
  const float* W3 = (const float*)d_in[10];
  const float* b3 = (const float*)d_in[11];

  float* ws = (float*)d_ws;
  uint32* keys     = (uint32*)ws;                 // 524288 u32 @0
  _Float16* AqG    = (_Float16*)(ws + 524288);    // 1048576 f16
  _Float16* BsG    = (_Float16*)(ws + 1048576);   // 131072 f16
  float* c0G       = ws + 1114112;                // 65536 fl
  _Float16* h1f_hi = (_Float16*)(ws + 1179648);   // 2097152 f16 each
  _Float16* h1f_lo = (_Float16*)(ws + 2228224);
  _Float16* h1C    = (_Float16*)(ws + 3276800);
  _Float16* w2f_hi = (_Float16*)(ws + 6422528);   // 65536 f16 each
  _Float16* w2f_lo = (_Float16*)(ws + 6455296);
  _Float16* w2tf_hi= (_Float16*)(ws + 6488064);
  _Float16* w2tf_lo= (_Float16*)(ws + 6520832);
  float* sdf_part  = ws + 6553600;                // 256
  float* ori_part  = ws + 6553856;                // 256
  float* eg2       = ws + 6554112;                // 512
  float* out = (float*)d_out;

  prep_all<<<608, 256, 0, stream>>>(sp, offp, nearp, W1, b1, W2,
                                    AqG, BsG, c0G,
                                    w2f_hi, w2f_lo, w2tf_hi, w2tf_lo,
                                    h1f_hi, h1f_lo, h1C);
  scan_knn2<<<2048, 256, 0, stream>>>((const float4*)BsG, (const float4*)AqG, c0G, keys);
  knn_finish<<<256, 256, 0, stream>>>(keys, sp, sn, offp, nearp, off_pred, near_pred, ori_part);
  gemm_fused<<<256, 512, 0, stream>>>(h1f_hi, h1f_lo, w2f_hi, w2f_lo,
                                      w2tf_hi, w2tf_lo, h1C, W1,
                                      b2, W3, b3, sn, sdf_part, eg2);
  finalize<<<1, 256, 0, stream>>>(sdf_part, ori_part, eg2, out);
}

// Round 15
// 79.001 us; speedup vs baseline: 1.8442x; 1.0523x over previous
//
#include <hip/hip_runtime.h>
#include <math.h>

typedef unsigned int uint32;

#define N_SURF 8192
#define M_QRY  32768
#define M_TOT  65536
#define HID    256

using f16x8  = __attribute__((ext_vector_type(8)))  _Float16;
using f32x16 = __attribute__((ext_vector_type(16))) float;

static __device__ __forceinline__ uint32 umin32(uint32 a, uint32 b) { return a < b ? a : b; }
static __device__ __forceinline__ uint32 umax32(uint32 a, uint32 b) { return a > b ? a : b; }

__device__ __forceinline__ void gload_lds16(const void* g, void* l) {
  __builtin_amdgcn_global_load_lds(
      (const __attribute__((address_space(1))) unsigned int*)g,
      (__attribute__((address_space(3))) unsigned int*)l, 16, 0, 0);
}

// MFMA with destination in plain "v"-class regs (gfx950 unified file).
static __device__ __forceinline__ f32x16 mfma_v(f16x8 a, f16x8 b, f32x16 c) {
  f32x16 d;
  asm("v_mfma_f32_32x32x16_f16 %0, %1, %2, %3"
      : "=&v"(d) : "v"(a), "v"(b), "v"(c));
  return d;
}

#define RMAP(r, half) (((r) & 3) + 8 * ((r) >> 2) + 4 * (half))

// ---- ws layout (float offsets) ----
// keys u32[524288] @0 ; AqG f16[1048576] @524288 ; BsG f16[131072] @1048576 ;
// c0G f32[65536] @1114112 ; h1f_hi @1179648 ; h1f_lo @2228224 ; h1C @3276800 ;
// w2f_hi @6422528 ; w2f_lo @6455296 ; w2tf_hi @6488064 ; w2tf_lo @6520832 ;
// sdf_part[256] @6553600 ; ori_part[128] @6553856 ; eg2[512] @6554112

// ---------------- K1: prep_q — query features + surface point frags (scan inputs) ----------------
__global__ __launch_bounds__(256) void prep_q(
    const float* __restrict__ sp,
    const float* __restrict__ offp, const float* __restrict__ nearp,
    _Float16* __restrict__ AqG, _Float16* __restrict__ BsG,
    float* __restrict__ c0G) {
  int bid = blockIdx.x, tid = threadIdx.x;
  if (bid < 256) {                    // ---- query features ----
    int q = bid * 256 + tid;
    const float* p = (q < M_QRY) ? (offp + q * 3) : (nearp + (q - M_QRY) * 3);
    float x = p[0], y = p[1], z = p[2];
    _Float16 hx = (_Float16)x, hy = (_Float16)y, hz = (_Float16)z;
    _Float16 lx = (_Float16)(x - (float)hx);
    _Float16 ly = (_Float16)(y - (float)hy);
    _Float16 lz = (_Float16)(z - (float)hz);
    float tx = (float)hx + (float)lx, ty = (float)hy + (float)ly, tz = (float)hz + (float)lz;
    _Float16 av[16] = {hx, hy, hz, lx, ly, lz, hx, hy, hz, lx, ly, lz,
                       (_Float16)1.0f, (_Float16)1.0f, (_Float16)1.0f, (_Float16)0.0f};
    float4* dst = (float4*)&AqG[(size_t)q * 16];
    dst[0] = *(float4*)&av[0];
    dst[1] = *(float4*)&av[8];
    c0G[q] = 0.5f * (tx * tx + ty * ty + tz * tz);
  } else {                            // ---- surface point features ----
    int i = (bid - 256) * 256 + tid;  // 0..8191
    float x = sp[i * 3 + 0], y = sp[i * 3 + 1], z = sp[i * 3 + 2];
    _Float16 hx = (_Float16)x, hy = (_Float16)y, hz = (_Float16)z;
    _Float16 lx = (_Float16)(x - (float)hx);
    _Float16 ly = (_Float16)(y - (float)hy);
    _Float16 lz = (_Float16)(z - (float)hz);
    float tx = (float)hx + (float)lx, ty = (float)hy + (float)ly, tz = (float)hz + (float)lz;
    float w = 0.5f * (tx * tx + ty * ty + tz * tz);
    _Float16 wh = (_Float16)w;
    float r1 = w - (float)wh;
    _Float16 wl = (_Float16)r1;
    _Float16 wll = (_Float16)(r1 - (float)wl);
    _Float16 nhx = -hx, nhy = -hy, nhz = -hz, nlx = -lx, nly = -ly, nlz = -lz;
    _Float16 b0[8] = {nhx, nhy, nhz, nhx, nhy, nhz, nlx, nly};            // k0..7
    _Float16 b1v[8] = {nlz, nlx, nly, nlz, wh, wl, wll, (_Float16)0.0f};  // k8..15
    int tile = i >> 5, pcol = i & 31;
    *(float4*)&BsG[(size_t)((tile * 2 + 0) * 32 + pcol) * 8] = *(float4*)&b0[0];
    *(float4*)&BsG[(size_t)((tile * 2 + 1) * 32 + pcol) * 8] = *(float4*)&b1v[0];
  }
}

// ---------------- K2: scan (blocks 0-2047) + gemm-prep (blocks 2048-2367) ----------------
#define TRACK2(d0v, d1v, s0v, s1v)                                        \
  _Pragma("unroll")                                                       \
  for (int r = 0; r < 16; r++) {                                          \
    uint32 kA, kB;                                                        \
    asm("v_and_or_b32 %0, %3, %5, %6\n\t"                                 \
        "v_and_or_b32 %1, %4, %5, %7\n\t"                                 \
        "v_min3_u32 %2, %2, %0, %1"                                       \
        : "=&v"(kA), "=&v"(kB), "+v"(b1[r])                               \
        : "v"(d0v[r]), "v"(d1v[r]), "v"(vmask), "s"(s0v), "s"(s1v));      \
  }

__global__ __launch_bounds__(256) void scan_prep(
    const float4* __restrict__ BsG,    // 8192*2 16B units, frag order
    const float4* __restrict__ AqG,
    const float* __restrict__ c0G,
    uint32* __restrict__ keys,         // [4][65536][2]
    // gemm-prep args
    const float* __restrict__ sp,
    const float* __restrict__ W1, const float* __restrict__ b1w,
    const float* __restrict__ W2,
    _Float16* __restrict__ w2f_hi, _Float16* __restrict__ w2f_lo,
    _Float16* __restrict__ w2tf_hi, _Float16* __restrict__ w2tf_lo,
    _Float16* __restrict__ h1f_hi, _Float16* __restrict__ h1f_lo,
    _Float16* __restrict__ h1C) {
  __shared__ __align__(16) float4 Bsh[2048];  // 32KB (2 x 1024 units)
  int tid = threadIdx.x;

  if (blockIdx.x >= 2048) {
    int bid2 = blockIdx.x - 2048;     // 0..319
    if (bid2 < 64) {                  // ---- W2 / W2^T fragment packs ----
      int u = bid2 * 256 + tid;       // 0..16383
      int uu = u & 8191;
      int lane = uu & 63, su = uu >> 6;
      int cb = su >> 4, s = su & 15;
      int nl = lane & 31, hf = lane >> 5;
      float v[8];
      if (u < 8192) {
#pragma unroll
        for (int e = 0; e < 8; e++) v[e] = W2[(s * 16 + hf * 8 + e) * 256 + cb * 32 + nl];
      } else {
#pragma unroll
        for (int e = 0; e < 8; e++) v[e] = W2[(cb * 32 + nl) * 256 + s * 16 + hf * 8 + e];
      }
      _Float16 hi[8], lo[8];
#pragma unroll
      for (int e = 0; e < 8; e++) {
        _Float16 h = (_Float16)v[e];
        hi[e] = h; lo[e] = (_Float16)(v[e] - (float)h);
      }
      _Float16* dh = (u < 8192) ? w2f_hi : w2tf_hi;
      _Float16* dl = (u < 8192) ? w2f_lo : w2tf_lo;
      *(float4*)&dh[(size_t)uu * 8] = *(float4*)hi;
      *(float4*)&dl[(size_t)uu * 8] = *(float4*)lo;
    } else {                          // ---- layer-1 h1 frags + h1C ----
      int rb = bid2 - 64;             // 0..255
      int row = rb * 32 + (tid >> 3);
      int oct = tid & 7;
      float px = sp[row * 3 + 0], py = sp[row * 3 + 1], pz = sp[row * 3 + 2];
#pragma unroll
      for (int it = 0; it < 4; ++it) {
        int j0 = it * 64 + oct * 8;
        _Float16 hh[8], hl[8];
#pragma unroll
        for (int e = 0; e < 8; e++) {
          int j = j0 + e;
          float z = fmaf(px, W1[j], fmaf(py, W1[256 + j], fmaf(pz, W1[512 + j], b1w[j])));
          float h = fmaxf(z, 0.f) + log1pf(expf(-fabsf(z)));
          _Float16 hi = (_Float16)h;
          hh[e] = hi; hl[e] = (_Float16)(h - (float)hi);
        }
        int s = it * 4 + (oct >> 1), hf = oct & 1;
        size_t uidx = ((size_t)(rb * 16 + s)) * 64 + (row & 31) + 32 * hf;
        *(float4*)&h1f_hi[uidx * 8] = *(float4*)hh;
        *(float4*)&h1f_lo[uidx * 8] = *(float4*)hl;
        *(float4*)&h1C[(size_t)row * 256 + j0] = *(float4*)hh;
      }
    }
    return;
  }

  // ================= SCAN path (r10 best) =================
  int lane = tid & 63, wid = tid >> 6;
  int col = lane & 31, half = lane >> 5;
  int seg = blockIdx.x >> 9;           // 0..3
  int qb  = blockIdx.x & 511;
  int qbase = qb * 128 + wid * 32;

  f16x8 afrag = ((const f16x8*)AqG)[(qbase + col) * 2 + half];
  f32x16 c0f;
#pragma unroll
  for (int r = 0; r < 16; r++) c0f[r] = c0G[qbase + RMAP(r, half)];
  uint32 b1[16];
#pragma unroll
  for (int r = 0; r < 16; r++) b1[r] = 0xFFFFFFFFu;

  const char* gseg = (const char*)(BsG + (size_t)seg * 4096);  // 2048 pts
  char* lbase = (char*)&Bsh[0];
#pragma unroll
  for (int i = 0; i < 4; i++)
    gload_lds16(gseg + (size_t)(0 * 1024 + i * 256 + tid) * 16,
                lbase + ((0 * 1024 + i * 256 + tid) * 16));
#pragma unroll
  for (int i = 0; i < 4; i++)
    gload_lds16(gseg + (size_t)(1 * 1024 + i * 256 + tid) * 16,
                lbase + ((1024 + i * 256 + tid) * 16));

  uint32 vmask = 0xFFFFE000u;
  int tseg = seg * 64;                 // global tile base (64 tiles / segment)
#pragma unroll 1
  for (int c = 0; c < 4; c++) {
    if (c < 3) asm volatile("s_waitcnt vmcnt(4)" ::: "memory");
    else       asm volatile("s_waitcnt vmcnt(0)" ::: "memory");
    __builtin_amdgcn_s_barrier();
    const f16x8* bbuf = (const f16x8*)&Bsh[(c & 1) * 1024];
    int tbase = tseg + c * 16;
    // A holds even pairs (tiles 4g+0,4g+1), B holds odd pairs (tiles 4g+2,4g+3).
    f16x8 fA0 = bbuf[0 * 64 + lane];
    f16x8 fA1 = bbuf[1 * 64 + lane];
    f32x16 dA0 = mfma_v(afrag, fA0, c0f);
    f32x16 dA1 = mfma_v(afrag, fA1, c0f);
    f16x8 fB0 = bbuf[2 * 64 + lane];
    f16x8 fB1 = bbuf[3 * 64 + lane];
    f32x16 dB0 = mfma_v(afrag, fB0, c0f);
    f32x16 dB1 = mfma_v(afrag, fB1, c0f);
#pragma unroll
    for (int g = 0; g < 3; g++) {
      TRACK2(dA0, dA1, tbase + 4 * g + 0, tbase + 4 * g + 1);
      fA0 = bbuf[(4 * g + 4) * 64 + lane];
      fA1 = bbuf[(4 * g + 5) * 64 + lane];
      dA0 = mfma_v(afrag, fA0, c0f);
      dA1 = mfma_v(afrag, fA1, c0f);
      TRACK2(dB0, dB1, tbase + 4 * g + 2, tbase + 4 * g + 3);
      fB0 = bbuf[(4 * g + 6) * 64 + lane];
      fB1 = bbuf[(4 * g + 7) * 64 + lane];
      dB0 = mfma_v(afrag, fB0, c0f);
      dB1 = mfma_v(afrag, fB1, c0f);
    }
    TRACK2(dA0, dA1, tbase + 12, tbase + 13);
    TRACK2(dB0, dB1, tbase + 14, tbase + 15);
    __builtin_amdgcn_s_barrier();
    if (c + 2 < 4) {
      int nc = c + 2;
#pragma unroll
      for (int i = 0; i < 4; i++)
        gload_lds16(gseg + (size_t)(nc * 1024 + i * 256 + tid) * 16,
                    lbase + (((nc & 1) * 1024 + i * 256 + tid) * 16));
    }
  }

  // tile-keys -> full-index keys: idx = tile*32 + col
#pragma unroll
  for (int r = 0; r < 16; r++) {
    uint32 t1 = b1[r];
    b1[r] = (t1 & 0xFFFFE000u) | (((t1 & 0xFFu) << 5) | (uint32)col);
  }
  uint32 b2[16];
#pragma unroll
  for (int r = 0; r < 16; r++) b2[r] = 0xFFFFFFFFu;
#pragma unroll
  for (int r = 0; r < 16; r++) {
#pragma unroll
    for (int m = 1; m <= 16; m <<= 1) {
      uint32 o1 = (uint32)__shfl_xor((int)b1[r], m, 64);
      uint32 o2 = (uint32)__shfl_xor((int)b2[r], m, 64);
      uint32 n1 = umin32(b1[r], o1);
      uint32 n2 = umin32(umax32(b1[r], o1), umin32(b2[r], o2));
      b1[r] = n1; b2[r] = n2;
    }
  }
  if (col == 0) {
#pragma unroll
    for (int r = 0; r < 16; r++) {
      int row = RMAP(r, half);
      keys[(size_t)seg * 131072 + (size_t)(qbase + row) * 2 + 0] = b1[r];
      keys[(size_t)seg * 131072 + (size_t)(qbase + row) * 2 + 1] = b2[r];
    }
  }
}

// ---------------- K3: fused GEMM (blocks 0-255) + knn_finish (blocks 256-383) ----------------
__global__ __launch_bounds__(512) void gemm_knn(
    const _Float16* __restrict__ h1f_hi, const _Float16* __restrict__ h1f_lo,
    const _Float16* __restrict__ w2f_hi, const _Float16* __restrict__ w2f_lo,
    const _Float16* __restrict__ w2tf_hi, const _Float16* __restrict__ w2tf_lo,
    const _Float16* __restrict__ h1C, const float* __restrict__ W1,
    const float* __restrict__ b2, const float* __restrict__ W3,
    const float* __restrict__ b3, const float* __restrict__ sn,
    float* __restrict__ sdf_part,         // [256]
    float* __restrict__ eg2,              // [256][2]
    // knn args
    const uint32* __restrict__ keys,
    const float* __restrict__ sp,
    const float* __restrict__ offp, const float* __restrict__ nearp,
    const float* __restrict__ off_pred, const float* __restrict__ near_pred,
    float* __restrict__ ori_part) {       // [128]
  __shared__ __align__(16) _Float16 tlds[8][2][32][40]; // 40KB
  __shared__ float predb[8][32];
  __shared__ float gb[8][32][3];
  int tid = threadIdx.x, lane = tid & 63, wid = tid >> 6;

  if (blockIdx.x >= 256) {
    // ================= knn_finish: 128 blocks x 512 threads =================
    int q = (blockIdx.x - 256) * 512 + tid;
    bool isOff = q < M_QRY;
    const float* qp = isOff ? (offp + q * 3) : (nearp + (q - M_QRY) * 3);
    float qx = qp[0], qy = qp[1], qz = qp[2];
    uint32 m1 = 0xFFFFFFFFu, m2 = 0xFFFFFFFFu;
#pragma unroll
    for (int s = 0; s < 4; s++) {
      uint32 k1 = keys[(size_t)s * 131072 + (size_t)q * 2 + 0];
      uint32 k2 = keys[(size_t)s * 131072 + (size_t)q * 2 + 1];
      m2 = umin32(m2, umax32(m1, k1)); m1 = umin32(m1, k1);
      m2 = umin32(m2, umax32(m1, k2)); m1 = umin32(m1, k2);
    }
    int i1 = (int)(m1 & 8191u), i2 = (int)(m2 & 8191u);
    float d1 = (qx - sp[i1 * 3 + 0]) * sn[i1 * 3 + 0] +
               (qy - sp[i1 * 3 + 1]) * sn[i1 * 3 + 1] +
               (qz - sp[i1 * 3 + 2]) * sn[i1 * 3 + 2];
    float d2 = (qx - sp[i2 * 3 + 0]) * sn[i2 * 3 + 0] +
               (qy - sp[i2 * 3 + 1]) * sn[i2 * 3 + 1] +
               (qz - sp[i2 * 3 + 2]) * sn[i2 * 3 + 2];
    float m = d1 + d2;
    float sg = (m > 0.f) ? 1.f : ((m < 0.f) ? -1.f : 0.f);
    float pred = isOff ? off_pred[q] : near_pred[q - M_QRY];
    float contrib = fmaxf(0.f, -pred * sg);

    float* red = (float*)tlds;
    red[tid] = contrib;
    __syncthreads();
    for (int s = 256; s > 0; s >>= 1) {
      if (tid < s) red[tid] += red[tid + s];
      __syncthreads();
    }
    if (tid == 0) ori_part[blockIdx.x - 256] = red[0];
    return;
  }

  // ================= GEMM path =================
  int rb = blockIdx.x;                    // 0..255
  int nl = lane & 31, half = lane >> 5;

  // ---------- phase 1: z2 = h1 @ W2 ----------
  {
    int cb = wid;
    f32x16 acc = {};
#pragma unroll
    for (int s = 0; s < 16; s++) {
      f16x8 ah = *(const f16x8*)&h1f_hi[(((size_t)rb * 16 + s) * 64 + lane) * 8];
      f16x8 al = *(const f16x8*)&h1f_lo[(((size_t)rb * 16 + s) * 64 + lane) * 8];
      f16x8 bh = *(const f16x8*)&w2f_hi[(((size_t)cb * 16 + s) * 64 + lane) * 8];
      f16x8 bl = *(const f16x8*)&w2f_lo[(((size_t)cb * 16 + s) * 64 + lane) * 8];
      acc = __builtin_amdgcn_mfma_f32_32x32x16_f16(ah, bh, acc, 0, 0, 0);
      acc = __builtin_amdgcn_mfma_f32_32x32x16_f16(al, bh, acc, 0, 0, 0);
      acc = __builtin_amdgcn_mfma_f32_32x32x16_f16(ah, bl, acc, 0, 0, 0);
    }
    int n = cb * 32 + nl;
    float b2n = b2[n], w3n = W3[n];
    float psum[16];
    _Float16 dh[16], dl[16];
#pragma unroll
    for (int r = 0; r < 16; r++) {
      float z = acc[r] + b2n;
      float h2 = fmaxf(z, 0.f) + log1pf(expf(-fabsf(z)));
      psum[r] = h2 * w3n;
      float dz2 = w3n * (1.f - expf(-h2));
      _Float16 hd = (_Float16)dz2;
      dh[r] = hd; dl[r] = (_Float16)(dz2 - (float)hd);
    }
#pragma unroll
    for (int r = 0; r < 16; r++) {
#pragma unroll
      for (int m = 1; m <= 16; m <<= 1) psum[r] += __shfl_xor(psum[r], m, 64);
    }
    if (nl == 0) {
#pragma unroll
      for (int r = 0; r < 16; r++) predb[cb][RMAP(r, half)] = psum[r];
    }
#pragma unroll
    for (int r = 0; r < 16; r++) {
      int rw = RMAP(r, half);
      tlds[wid][0][rw][nl] = dh[r];
      tlds[wid][1][rw][nl] = dl[r];
    }
  }
  __syncthreads();

  // ---------- phase 2: dh1 = dz2 @ W2^T ; grad ----------
  {
    int cb2 = wid;
    f32x16 acc = {};
#pragma unroll
    for (int s = 0; s < 16; s++) {
      f16x8 ah = *(const f16x8*)&tlds[s >> 1][0][nl][(s & 1) * 16 + half * 8];
      f16x8 al = *(const f16x8*)&tlds[s >> 1][1][nl][(s & 1) * 16 + half * 8];
      f16x8 bh = *(const f16x8*)&w2tf_hi[(((size_t)cb2 * 16 + s) * 64 + lane) * 8];
      f16x8 bl = *(const f16x8*)&w2tf_lo[(((size_t)cb2 * 16 + s) * 64 + lane) * 8];
      acc = __builtin_amdgcn_mfma_f32_32x32x16_f16(ah, bh, acc, 0, 0, 0);
      acc = __builtin_amdgcn_mfma_f32_32x32x16_f16(al, bh, acc, 0, 0, 0);
      acc = __builtin_amdgcn_mfma_f32_32x32x16_f16(ah, bl, acc, 0, 0, 0);
    }
    int j = cb2 * 32 + nl;
    float w10 = W1[j], w11 = W1[256 + j], w12 = W1[512 + j];
    float gx[16], gy[16], gz[16];
#pragma unroll
    for (int r = 0; r < 16; r++) {
      int row = rb * 32 + RMAP(r, half);
      float h1 = (float)h1C[(size_t)row * 256 + j];
      float s1 = 1.f - expf(-h1);
      float dz1 = acc[r] * s1;
      gx[r] = dz1 * w10; gy[r] = dz1 * w11; gz[r] = dz1 * w12;
    }
#pragma unroll
    for (int r = 0; r < 16; r++) {
#pragma unroll
      for (int m = 1; m <= 16; m <<= 1) {
        gx[r] += __shfl_xor(gx[r], m, 64);
        gy[r] += __shfl_xor(gy[r], m, 64);
        gz[r] += __shfl_xor(gz[r], m, 64);
      }
    }
    if (nl == 0) {
#pragma unroll
      for (int r = 0; r < 16; r++) {
        int row32 = RMAP(r, half);
        gb[cb2][row32][0] = gx[r];
        gb[cb2][row32][1] = gy[r];
        gb[cb2][row32][2] = gz[r];
      }
    }
  }
  __syncthreads();

  if (tid < 64) {
    int row32 = tid & 31;
    float p = b3[0];
    float sgx = 0.f, sgy = 0.f, sgz = 0.f;
#pragma unroll
    for (int c8 = 0; c8 < 8; c8++) {
      p += predb[c8][row32];
      sgx += gb[c8][row32][0];
      sgy += gb[c8][row32][1];
      sgz += gb[c8][row32][2];
    }
    int row = rb * 32 + row32;
    float n0 = sn[row * 3 + 0], n1 = sn[row * 3 + 1], n2 = sn[row * 3 + 2];
    float nrm = sqrtf(sgx * sgx + sgy * sgy + sgz * sgz);
    float ee = (nrm - 1.f) * (nrm - 1.f);
    float gg = (sgx - n0) * (sgx - n0) + (sgy - n1) * (sgy - n1) + (sgz - n2) * (sgz - n2);
    float vee = (tid < 32) ? ee : 0.f;
    float vgg = (tid < 32) ? gg : 0.f;
    float vsq = (tid < 32) ? p * p : 0.f;
    for (int off = 32; off > 0; off >>= 1) {
      vee += __shfl_down(vee, off);
      vgg += __shfl_down(vgg, off);
      vsq += __shfl_down(vsq, off);
    }
    if (tid == 0) {
      sdf_part[rb] = vsq;
      eg2[rb * 2 + 0] = vee;
      eg2[rb * 2 + 1] = vgg;
    }
  }
}

// ---------------- K4: final reduce (tiny) ----------------
__global__ __launch_bounds__(256) void finalize(
    const float* __restrict__ sdf_part,   // 256
    const float* __restrict__ ori_part,   // 128 (64 off, 64 near)
    const float* __restrict__ eg2,        // 512
    float* __restrict__ out) {
  __shared__ float red[256];
  int t = threadIdx.x;
  float s_sdf = sdf_part[t];
  float s_ori = (t < 64) ? ori_part[t] : 0.f;
  float s_near = (t < 64) ? ori_part[64 + t] : 0.f;
  float s_eik = eg2[t * 2 + 0];
  float s_gn = eg2[t * 2 + 1];

  float S[5];
  float vals[5] = {s_sdf, s_ori, s_near, s_eik, s_gn};
  for (int v = 0; v < 5; v++) {
    red[t] = vals[v];
    __syncthreads();
    for (int s = 128; s > 0; s >>= 1) {
      if (t < s) red[t] += red[t + s];
      __syncthreads();
    }
    S[v] = red[0];
    __syncthreads();
  }
  if (t == 0) {
    float sdf = S[0] / 8192.f;
    float ori = S[1] / 32768.f;
    float nearo = S[2] / 32768.f;
    float eik = S[3] / 8192.f;
    float gn = S[4] / 24576.f;
    out[0] = 7000.f * sdf + 600.f * eik + 500.f * ori + 10.f * nearo + 200.f * gn;
    out[1] = sdf;
    out[2] = eik;
    out[3] = ori;
    out[4] = nearo;
    out[5] = gn;
  }
}

extern "C" void kernel_launch(void* const* d_in, const int* in_sizes, int n_in,
                              void* d_out, int out_size, void* d_ws, size_t ws_size,
                              hipStream_t stream) {
  const float* sp       = (const float*)d_in[0];
  const float* sn       = (const float*)d_in[1];
  const float* offp     = (const float*)d_in[2];
  const float* nearp    = (const float*)d_in[3];
  const float* off_pred = (const float*)d_in[4];
  const float* near_pred= (const float*)d_in[5];
  const float* W1 = (const float*)d_in[6];
  const float* b1 = (const float*)d_in[7];
  const float* W2 = (const float*)d_in[8];
  const float* b2 = (const float*)d_in[9];
  const float* W3 = (const float*)d_in[10];
  const float* b3 = (const float*)d_in[11];

  float* ws = (float*)d_ws;
  uint32* keys     = (uint32*)ws;                 // 524288 u32 @0
  _Float16* AqG    = (_Float16*)(ws + 524288);    // 1048576 f16
  _Float16* BsG    = (_Float16*)(ws + 1048576);   // 131072 f16
  float* c0G       = ws + 1114112;                // 65536 fl
  _Float16* h1f_hi = (_Float16*)(ws + 1179648);   // 2097152 f16 each
  _Float16* h1f_lo = (_Float16*)(ws + 2228224);
  _Float16* h1C    = (_Float16*)(ws + 3276800);
  _Float16* w2f_hi = (_Float16*)(ws + 6422528);   // 65536 f16 each
  _Float16* w2f_lo = (_Float16*)(ws + 6455296);
  _Float16* w2tf_hi= (_Float16*)(ws + 6488064);
  _Float16* w2tf_lo= (_Float16*)(ws + 6520832);
  float* sdf_part  = ws + 6553600;                // 256
  float* ori_part  = ws + 6553856;                // 128
  float* eg2       = ws + 6554112;                // 512
  float* out = (float*)d_out;

  prep_q<<<288, 256, 0, stream>>>(sp, offp, nearp, AqG, BsG, c0G);
  scan_prep<<<2368, 256, 0, stream>>>((const float4*)BsG, (const float4*)AqG, c0G, keys,
                                      sp, W1, b1, W2,
                                      w2f_hi, w2f_lo, w2tf_hi, w2tf_lo,
                                      h1f_hi, h1f_lo, h1C);
  gemm_knn<<<384, 512, 0, stream>>>(h1f_hi, h1f_lo, w2f_hi, w2f_lo,
                                    w2tf_hi, w2tf_lo, h1C, W1,
                                    b2, W3, b3, sn, sdf_part, eg2,
                                    keys, sp, offp, nearp, off_pred, near_pred,
                                    ori_part);
  finalize<<<1, 256, 0, stream>>>(sdf_part, ori_part, eg2, out);
}